// Round 12
// baseline (169.786 us; speedup 1.0000x reference)
//
#include <hip/hip_runtime.h>
#include <hip/hip_bf16.h>
#include <float.h>

#define N_NODES 100000
#define HID     512
#define NGRAPH  1024
#define NMB     782                         // ceil(100000/128) M-blocks
#define NBLK    (NMB * 2)                   // x2 N-halves (256 cols each)

typedef __bf16 bf16_t;
typedef bf16_t bf16x8 __attribute__((ext_vector_type(8)));
typedef float  f32x4  __attribute__((ext_vector_type(4)));

// global -> LDS direct DMA, 16B/lane; dest = wave-uniform base + lane*16.
#define GLOAD_LDS16(g, l)                                                        \
    __builtin_amdgcn_global_load_lds(                                            \
        (const __attribute__((address_space(1))) unsigned int*)(g),              \
        (__attribute__((address_space(3))) unsigned int*)(l), 16, 0, 0)

// Branch-free gelu: erf via Abramowitz-Stegun 7.1.26 (|err|<=1.5e-7).
__device__ __forceinline__ float fast_gelu(float x) {
    const float z = __builtin_fabsf(x) * 0.70710678118654752f;
    const float t = __fdividef(1.0f, __builtin_fmaf(0.3275911f, z, 1.0f));
    float p = __builtin_fmaf(1.061405429f, t, -1.453152027f);
    p = __builtin_fmaf(p, t, 1.421413741f);
    p = __builtin_fmaf(p, t, -0.284496736f);
    p = __builtin_fmaf(p, t, 0.254829592f);
    p *= t;
    const float e    = __expf(-z * z);
    const float erfz = __builtin_fmaf(-p, e, 1.0f);
    const float s    = __builtin_copysignf(erfz, x);
    return 0.5f * x * (1.0f + s);
}

// ---- Kernel 0: W1 [K][N] f32 -> plain transpose wt[col][k] bf16 -------------
__global__ void __launch_bounds__(256) k_w1t(const float* __restrict__ w1,
                                             bf16_t* __restrict__ wt) {
    const int idx = blockIdx.x * 256 + threadIdx.x;   // 0..32767 (8-elem units)
    const int col = idx >> 6;
    const int k0  = (idx & 63) * 8;
    bf16x8 v;
    #pragma unroll
    for (int e = 0; e < 8; ++e)
        v[e] = (bf16_t)w1[(size_t)(k0 + e) * HID + col];
    *reinterpret_cast<bf16x8*>(wt + (size_t)col * HID + k0) = v;
}

// ---- Kernel 1: fused GEMM + gelu + dot(W2) -> gpart (m97-style) -------------
// Tile 128M x 256N x BK=32. 512 thr = 8 waves (2M x 4N), wave owns 64x64
// (acc[4][4]). B staged via global_load_lds (dbuf 2x16KB, linear dest +
// pre-swizzled source); A reg-staged f32->bf16 (dbuf 2x8KB, T14 issue-early /
// write-late). One barrier per K-step. LDS 52KB.
__global__ void __launch_bounds__(512, 4) k_gemm_gate(const float* __restrict__ h,
                                                      const bf16_t* __restrict__ wt,
                                                      const float* __restrict__ b1,
                                                      const float* __restrict__ w2,
                                                      float* __restrict__ gpart) {
    __shared__ __align__(16) bf16_t As[2][128 * 32];   // 8KB each: [row][slot], 64B rows
    __shared__ __align__(16) bf16_t Bs[2][256 * 32];   // 16KB each: [col][slot], 64B rows
    __shared__ float gp[8][128];

    const int tid  = threadIdx.x;
    const int lane = tid & 63;
    const int wv   = tid >> 6;     // 0..7
    const int wm   = wv >> 2;      // 0..1 : rows [wm*64, +64)
    const int wn   = wv & 3;       // 0..3 : cols [wn*64, +64)
    const int l15  = lane & 15;
    const int l4   = lane >> 4;    // 0..3

    const int bidx = blockIdx.x;
    const int brow = (bidx >> 1) * 128;
    const int bcol = (bidx & 1) * 256;

    // ---- A staging geometry: thread -> (row, kc) ; slot = kc ^ (row&3) ----
    const int  arow  = tid >> 2;
    const int  akc   = tid & 3;
    const int  agrow = brow + arow;
    const bool aval  = agrow < N_NODES;
    const float*   aptr = h + (size_t)agrow * HID + akc * 8;
    const unsigned aoff = (unsigned)(arow * 64 + ((akc ^ (arow & 3)) * 16));

    // ---- B staging geometry: 2 glds per wave; unit u -> (col=u>>2, s=u&3);
    //      source pre-swizzled so LDS slot s holds data kc = s ^ (col&3) ----
    const int u0 = wv * 128 + lane;
    const int u1 = u0 + 64;
    const int c0 = u0 >> 2, s0 = u0 & 3;
    const int c1 = u1 >> 2, s1 = u1 & 3;
    const bf16_t* bsrc0 = wt + (size_t)(bcol + c0) * HID + (s0 ^ (c0 & 3)) * 8;
    const bf16_t* bsrc1 = wt + (size_t)(bcol + c1) * HID + (s1 ^ (c1 & 3)) * 8;
    const unsigned bdst0 = (unsigned)(wv * 128) * 16;
    const unsigned bdst1 = bdst0 + 64 * 16;

    // ================= prologue: stage step 0 into buffer 0 ====================
    {
        GLOAD_LDS16(bsrc0, (char*)&Bs[0][0] + bdst0);
        GLOAD_LDS16(bsrc1, (char*)&Bs[0][0] + bdst1);
        f32x4 a0 = {0.f, 0.f, 0.f, 0.f}, a1 = a0;
        if (aval) {
            const f32x4* p = reinterpret_cast<const f32x4*>(aptr);
            a0 = p[0]; a1 = p[1];
        }
        bf16x8 v;
        #pragma unroll
        for (int j = 0; j < 4; ++j) { v[j] = (bf16_t)a0[j]; v[4 + j] = (bf16_t)a1[j]; }
        *reinterpret_cast<bf16x8*>((char*)&As[0][0] + aoff) = v;
    }
    __syncthreads();

    // ================= K loop: 16 steps of 32, dbuf, one barrier/step ==========
    f32x4 acc[4][4] = {};
    int cur = 0;
    for (int t = 0; t < 16; ++t) {
        const int  nxt = cur ^ 1;
        const bool pf  = t < 15;

        // issue-early: next step's B DMA + A global loads
        f32x4 p0 = {0.f, 0.f, 0.f, 0.f}, p1 = p0;
        if (pf) {
            const int k0n = (t + 1) * 32;
            GLOAD_LDS16(bsrc0 + k0n, (char*)&Bs[nxt][0] + bdst0);
            GLOAD_LDS16(bsrc1 + k0n, (char*)&Bs[nxt][0] + bdst1);
            if (aval) {
                const f32x4* p = reinterpret_cast<const f32x4*>(aptr + k0n);
                p0 = p[0]; p1 = p[1];
            }
        }

        // fragment reads from buffer cur
        const char* Ab = (const char*)&As[cur][0];
        const char* Bb = (const char*)&Bs[cur][0];
        bf16x8 af[4], bfr[4];
        #pragma unroll
        for (int mf = 0; mf < 4; ++mf) {
            const int row = wm * 64 + mf * 16 + l15;
            af[mf] = *reinterpret_cast<const bf16x8*>(
                Ab + row * 64 + ((l4 ^ (row & 3)) * 16));
        }
        #pragma unroll
        for (int nf = 0; nf < 4; ++nf) {
            const int col = wn * 64 + nf * 16 + l15;
            bfr[nf] = *reinterpret_cast<const bf16x8*>(
                Bb + col * 64 + ((l4 ^ (col & 3)) * 16));
        }
        #pragma unroll
        for (int mf = 0; mf < 4; ++mf)
            #pragma unroll
            for (int nf = 0; nf < 4; ++nf)
                acc[mf][nf] = __builtin_amdgcn_mfma_f32_16x16x32_bf16(
                    af[mf], bfr[nf], acc[mf][nf], 0, 0, 0);

        // write-late: cvt + swizzled ds_write of next A tile
        if (pf) {
            bf16x8 v;
            #pragma unroll
            for (int j = 0; j < 4; ++j) { v[j] = (bf16_t)p0[j]; v[4 + j] = (bf16_t)p1[j]; }
            *reinterpret_cast<bf16x8*>((char*)&As[nxt][0] + aoff) = v;
        }
        __syncthreads();   // drains glds (vmcnt) + ds_write (lgkm)
        cur = nxt;
    }

    // ================= epilogue: fast_gelu(acc+b1)*w2, reduce wave's 64 cols ===
    float pr[16];
    #pragma unroll
    for (int i = 0; i < 16; ++i) pr[i] = 0.f;
    #pragma unroll
    for (int nf = 0; nf < 4; ++nf) {
        const int cg    = bcol + wn * 64 + nf * 16 + l15;
        const float b1v = b1[cg];
        const float w2v = w2[cg];
        #pragma unroll
        for (int mf = 0; mf < 4; ++mf) {
            #pragma unroll
            for (int rr = 0; rr < 4; ++rr) {
                const float ge = fast_gelu(acc[mf][nf][rr] + b1v);
                pr[mf * 4 + rr] = fmaf(ge, w2v, pr[mf * 4 + rr]);
            }
        }
    }
    #pragma unroll
    for (int i = 0; i < 16; ++i) {
        float v = pr[i];
        v += __shfl_xor(v, 1);
        v += __shfl_xor(v, 2);
        v += __shfl_xor(v, 4);
        v += __shfl_xor(v, 8);
        pr[i] = v;
    }
    if (l15 == 0) {
        #pragma unroll
        for (int mf = 0; mf < 4; ++mf)
            #pragma unroll
            for (int rr = 0; rr < 4; ++rr)
                gp[wv][wm * 64 + mf * 16 + l4 * 4 + rr] = pr[mf * 4 + rr];
    }
    __syncthreads();
    if (tid < 128) {
        const int grow = brow + tid;
        if (grow < N_NODES) {
            const int grp = tid >> 6;   // rows 0..63 -> waves 0..3 ; 64..127 -> 4..7
            float s = 0.f;
            #pragma unroll
            for (int j = 0; j < 4; ++j) s += gp[grp * 4 + j][tid];
            gpart[(size_t)(bidx & 1) * N_NODES + grow] = s;
        }
    }
}

// ---- Kernel 2: combine N-half partials + b2 ---------------------------------
__global__ void __launch_bounds__(256) k_gate_reduce(const float* __restrict__ gpart,
                                                     const float* __restrict__ b2,
                                                     float* __restrict__ gate) {
    int i = blockIdx.x * 256 + threadIdx.x;
    if (i < N_NODES) gate[i] = gpart[i] + gpart[N_NODES + i] + b2[0];
}

// ---- Kernel 3: segment softmax + weighted pool ------------------------------
__global__ void __launch_bounds__(256) k_pool(const float* __restrict__ h,
                                              const int* __restrict__ bv,
                                              const float* __restrict__ gate,
                                              float* __restrict__ out) {
    const int g   = blockIdx.x;
    const int tid = threadIdx.x;
    __shared__ int   s_bounds[2];
    __shared__ float s_red[4];
    __shared__ float s_alpha[256];

    if (tid == 0) {
        int lo = 0, hi = N_NODES;
        while (lo < hi) { int mid = (lo + hi) >> 1; if (bv[mid] < g) lo = mid + 1; else hi = mid; }
        s_bounds[0] = lo;
        int lo2 = lo, hi2 = N_NODES;
        while (lo2 < hi2) { int mid = (lo2 + hi2) >> 1; if (bv[mid] < g + 1) lo2 = mid + 1; else hi2 = mid; }
        s_bounds[1] = lo2;
    }
    __syncthreads();
    const int start = s_bounds[0], end = s_bounds[1];

    float2 acc = make_float2(0.f, 0.f);
    if (start < end) {
        const int lane = tid & 63, wv = tid >> 6;
        float lm = -FLT_MAX;
        for (int i = start + tid; i < end; i += 256) lm = fmaxf(lm, gate[i]);
        #pragma unroll
        for (int o = 32; o; o >>= 1) lm = fmaxf(lm, __shfl_xor(lm, o));
        if (lane == 0) s_red[wv] = lm;
        __syncthreads();
        const float m = fmaxf(fmaxf(s_red[0], s_red[1]), fmaxf(s_red[2], s_red[3]));
        __syncthreads();
        float ls = 0.f;
        for (int i = start + tid; i < end; i += 256) ls += expf(gate[i] - m);
        #pragma unroll
        for (int o = 32; o; o >>= 1) ls += __shfl_xor(ls, o);
        if (lane == 0) s_red[wv] = ls;
        __syncthreads();
        const float inv = 1.f / (s_red[0] + s_red[1] + s_red[2] + s_red[3]);
        const float* hcol = h + tid * 2;
        for (int base = start; base < end; base += 256) {
            const int j = base + tid;
            const float av = (j < end) ? expf(gate[j] - m) * inv : 0.f;
            __syncthreads();
            s_alpha[tid] = av;
            __syncthreads();
            const int cnt = min(256, end - base);
            for (int jj = 0; jj < cnt; ++jj) {
                const float a = s_alpha[jj];
                const float2 hv = *reinterpret_cast<const float2*>(
                    hcol + (size_t)(base + jj) * HID);
                acc.x = fmaf(a, hv.x, acc.x);
                acc.y = fmaf(a, hv.y, acc.y);
            }
        }
    }
    *reinterpret_cast<float2*>(out + (size_t)g * HID + tid * 2) = acc;
}

// ---- launcher ---------------------------------------------------------------
extern "C" void kernel_launch(void* const* d_in, const int* in_sizes, int n_in,
                              void* d_out, int out_size, void* d_ws, size_t ws_size,
                              hipStream_t stream) {
    const float* h  = (const float*)d_in[0];
    const int*   bv = (const int*)d_in[1];
    const float* W1 = (const float*)d_in[2];
    const float* b1 = (const float*)d_in[3];
    const float* W2 = (const float*)d_in[4];
    const float* b2 = (const float*)d_in[5];
    float* out = (float*)d_out;

    char* ws = (char*)d_ws;
    bf16_t* wt    = (bf16_t*)ws;                       // 512*512*2 = 524288 B
    float*  gpart = (float*)(ws + 524288);             // 2*100000*4 = 800000 B
    float*  gate  = (float*)(ws + 524288 + 800000);    // 400000 B

    k_w1t<<<dim3(128), dim3(256), 0, stream>>>(W1, wt);
    k_gemm_gate<<<dim3(NBLK), dim3(512), 0, stream>>>(h, wt, b1, W2, gpart);
    k_gate_reduce<<<dim3((N_NODES + 255) / 256), dim3(256), 0, stream>>>(gpart, b2, gate);
    k_pool<<<dim3(NGRAPH), dim3(256), 0, stream>>>(h, bv, gate, out);
}

// Round 13
// 141.339 us; speedup vs baseline: 1.2013x; 1.2013x over previous
//
#include <hip/hip_runtime.h>
#include <hip/hip_bf16.h>
#include <float.h>

#define N_NODES 100000
#define HID     512
#define NGRAPH  1024
#define BM      48            // rows per block
#define NBLK    ((N_NODES + BM - 1) / BM)   // 2084

typedef __bf16 bf16_t;
typedef bf16_t bf16x8 __attribute__((ext_vector_type(8)));
typedef float  f32x4  __attribute__((ext_vector_type(4)));

// Branch-free gelu: erf via Abramowitz-Stegun 7.1.26 (|err|<=1.5e-7).
__device__ __forceinline__ float fast_gelu(float x) {
    const float z = __builtin_fabsf(x) * 0.70710678118654752f;
    const float t = __fdividef(1.0f, __builtin_fmaf(0.3275911f, z, 1.0f));
    float p = __builtin_fmaf(1.061405429f, t, -1.453152027f);
    p = __builtin_fmaf(p, t, 1.421413741f);
    p = __builtin_fmaf(p, t, -0.284496736f);
    p = __builtin_fmaf(p, t, 0.254829592f);
    p *= t;
    const float e    = __expf(-z * z);
    const float erfz = __builtin_fmaf(-p, e, 1.0f);
    const float s    = __builtin_copysignf(erfz, x);
    return 0.5f * x * (1.0f + s);
}

// ---- Kernel 0: W1 [K][N] f32 -> tiled bf16 B: unit u=(kt*4+g)*512+col holds
// bf16x8 = W1[kt*32+g*8+e][col], e=0..7 ---------------------------------------
__global__ void __launch_bounds__(256) k_w1t_tiled(const float* __restrict__ w1,
                                                   bf16_t* __restrict__ bt) {
    const int u   = blockIdx.x * 256 + threadIdx.x;   // 0 .. 32767
    const int col = u & 511;
    const int g4  = u >> 9;
    const int k0  = g4 * 8;
    bf16x8 v;
    #pragma unroll
    for (int e = 0; e < 8; ++e)
        v[e] = (bf16_t)w1[(size_t)(k0 + e) * HID + col];
    *reinterpret_cast<bf16x8*>(bt + (size_t)u * 8) = v;
}

// ---- Kernel 1: fused GEMM + gelu + dot(W2) -> gate --------------------------
// R11 structure (8 waves, 48x64 wave tile, A resident in LDS, B direct L2->reg,
// barrier-free staggered K-loop) with ONE change: the stagger phase no longer
// depends on blockIdx. Wave wv of EVERY block starts at kt0 = (2*wv)&15, so the
// same-wv waves of co-resident blocks traverse the IDENTICAL 64KB B stream in
// lock-step -> second wave's B loads hit L1 (4KB/iter << 32KB L1), halving the
// per-CU L1 line-request pressure that limits this kernel. Cross-wave stagger
// (2*wv spreads 8 waves over 16 phases) still decorrelates pipe bursts.
__global__ void __launch_bounds__(512, 2) k_gemm_gate(const float* __restrict__ h,
                                                      const bf16_t* __restrict__ bt,
                                                      const float* __restrict__ b1,
                                                      const float* __restrict__ w2,
                                                      const float* __restrict__ b2,
                                                      float* __restrict__ gate) {
    __shared__ __align__(16) bf16_t As[BM * HID];   // 48KB: [48 rows][512 k], swizzled
    __shared__ float gp[8][BM];                     // per-wave row partials

    const int tid  = threadIdx.x;
    const int lane = tid & 63;
    const int wv   = tid >> 6;     // 0..7 : wave owns cols [wv*64, wv*64+64)
    const int l15  = lane & 15;
    const int l4   = lane >> 4;    // 0..3

    const int brow = blockIdx.x * BM;

    // ================= stage A: 48 rows x 2KB, coalesced =======================
    #pragma unroll
    for (int i = 0; i < 6; ++i) {
        const int idx = i * 512 + tid;
        const int row = idx >> 6;
        const int cu  = idx & 63;
        const int grow = brow + row;
        f32x4 s0 = f32x4{0.f, 0.f, 0.f, 0.f}, s1 = s0;
        if (grow < N_NODES) {
            const f32x4* p = reinterpret_cast<const f32x4*>(
                h + (size_t)grow * HID + cu * 8);
            s0 = p[0];
            s1 = p[1];
        }
        bf16x8 v;
        #pragma unroll
        for (int j = 0; j < 4; ++j) { v[j] = (bf16_t)s0[j]; v[4 + j] = (bf16_t)s1[j]; }
        *reinterpret_cast<bf16x8*>(
            (char*)As + row * 1024 + ((cu ^ (row & 7)) * 16)) = v;
    }
    __syncthreads();   // the ONLY barrier before the epilogue

    // ================= K loop: 16 tiles of 32, wave-staggered, barrier-free ====
    // B unit for (kt, nf): bbase + kt*16384 + nf*128 (bf16 elements)
    const bf16_t* bbase = bt + ((size_t)l4 * 512 + wv * 64 + l15) * 8;
    const char*   abase = (const char*)As + l15 * 1024;   // + mf*16384 + chunkoff
    const int     sh    = (wv << 1) & 15;   // block-INDEPENDENT phase offset
    f32x4 acc[3][4] = {};
    #pragma unroll
    for (int t = 0; t < 16; ++t) {
        const int kt = (t + sh) & 15;
        bf16x8 bfr[4];
        #pragma unroll
        for (int nf = 0; nf < 4; ++nf)
            bfr[nf] = *reinterpret_cast<const bf16x8*>(
                bbase + (size_t)kt * 16384 + nf * 128);
        const int chunkoff = ((kt * 4 + l4) ^ (l15 & 7)) * 16;
        bf16x8 af[3];
        #pragma unroll
        for (int mf = 0; mf < 3; ++mf)
            af[mf] = *reinterpret_cast<const bf16x8*>(abase + mf * 16384 + chunkoff);
        #pragma unroll
        for (int mf = 0; mf < 3; ++mf)
            #pragma unroll
            for (int nf = 0; nf < 4; ++nf)
                acc[mf][nf] = __builtin_amdgcn_mfma_f32_16x16x32_bf16(
                    af[mf], bfr[nf], acc[mf][nf], 0, 0, 0);
    }

    // ================= epilogue: fast_gelu(acc+b1)*w2, reduce 512 cols =========
    float pr[12];
    #pragma unroll
    for (int i = 0; i < 12; ++i) pr[i] = 0.f;
    #pragma unroll
    for (int nf = 0; nf < 4; ++nf) {
        const int cg    = wv * 64 + nf * 16 + l15;
        const float b1v = b1[cg];
        const float w2v = w2[cg];
        #pragma unroll
        for (int mf = 0; mf < 3; ++mf) {
            #pragma unroll
            for (int rr = 0; rr < 4; ++rr) {
                const float ge = fast_gelu(acc[mf][nf][rr] + b1v);
                pr[mf * 4 + rr] = fmaf(ge, w2v, pr[mf * 4 + rr]);
            }
        }
    }
    #pragma unroll
    for (int i = 0; i < 12; ++i) {
        float v = pr[i];
        v += __shfl_xor(v, 1);
        v += __shfl_xor(v, 2);
        v += __shfl_xor(v, 4);
        v += __shfl_xor(v, 8);
        pr[i] = v;
    }
    if (l15 == 0) {
        #pragma unroll
        for (int mf = 0; mf < 3; ++mf)
            #pragma unroll
            for (int rr = 0; rr < 4; ++rr)
                gp[wv][mf * 16 + l4 * 4 + rr] = pr[mf * 4 + rr];
    }
    __syncthreads();
    if (tid < BM) {
        const int grow = brow + tid;
        if (grow < N_NODES) {
            float s = b2[0];
            #pragma unroll
            for (int w = 0; w < 8; ++w) s += gp[w][tid];
            gate[grow] = s;
        }
    }
}

// ---- Kernel 2: segment softmax + weighted pool ------------------------------
__global__ void __launch_bounds__(256) k_pool(const float* __restrict__ h,
                                              const int* __restrict__ bv,
                                              const float* __restrict__ gate,
                                              float* __restrict__ out) {
    const int g   = blockIdx.x;
    const int tid = threadIdx.x;
    __shared__ int   s_bounds[2];
    __shared__ float s_red[4];
    __shared__ float s_alpha[256];

    if (tid == 0) {
        int lo = 0, hi = N_NODES;
        while (lo < hi) { int mid = (lo + hi) >> 1; if (bv[mid] < g) lo = mid + 1; else hi = mid; }
        s_bounds[0] = lo;
        int lo2 = lo, hi2 = N_NODES;
        while (lo2 < hi2) { int mid = (lo2 + hi2) >> 1; if (bv[mid] < g + 1) lo2 = mid + 1; else hi2 = mid; }
        s_bounds[1] = lo2;
    }
    __syncthreads();
    const int start = s_bounds[0], end = s_bounds[1];

    float2 acc = make_float2(0.f, 0.f);
    if (start < end) {
        const int lane = tid & 63, wv = tid >> 6;
        float lm = -FLT_MAX;
        for (int i = start + tid; i < end; i += 256) lm = fmaxf(lm, gate[i]);
        #pragma unroll
        for (int o = 32; o; o >>= 1) lm = fmaxf(lm, __shfl_xor(lm, o));
        if (lane == 0) s_red[wv] = lm;
        __syncthreads();
        const float m = fmaxf(fmaxf(s_red[0], s_red[1]), fmaxf(s_red[2], s_red[3]));
        __syncthreads();
        float ls = 0.f;
        for (int i = start + tid; i < end; i += 256) ls += expf(gate[i] - m);
        #pragma unroll
        for (int o = 32; o; o >>= 1) ls += __shfl_xor(ls, o);
        if (lane == 0) s_red[wv] = ls;
        __syncthreads();
        const float inv = 1.f / (s_red[0] + s_red[1] + s_red[2] + s_red[3]);
        const float* hcol = h + tid * 2;
        for (int base = start; base < end; base += 256) {
            const int j = base + tid;
            const float av = (j < end) ? expf(gate[j] - m) * inv : 0.f;
            __syncthreads();
            s_alpha[tid] = av;
            __syncthreads();
            const int cnt = min(256, end - base);
            for (int jj = 0; jj < cnt; ++jj) {
                const float a = s_alpha[jj];
                const float2 hv = *reinterpret_cast<const float2*>(
                    hcol + (size_t)(base + jj) * HID);
                acc.x = fmaf(a, hv.x, acc.x);
                acc.y = fmaf(a, hv.y, acc.y);
            }
        }
    }
    *reinterpret_cast<float2*>(out + (size_t)g * HID + tid * 2) = acc;
}

// ---- launcher ---------------------------------------------------------------
extern "C" void kernel_launch(void* const* d_in, const int* in_sizes, int n_in,
                              void* d_out, int out_size, void* d_ws, size_t ws_size,
                              hipStream_t stream) {
    const float* h  = (const float*)d_in[0];
    const int*   bv = (const int*)d_in[1];
    const float* W1 = (const float*)d_in[2];
    const float* b1 = (const float*)d_in[3];
    const float* W2 = (const float*)d_in[4];
    const float* b2 = (const float*)d_in[5];
    float* out = (float*)d_out;

    char* ws = (char*)d_ws;
    bf16_t* bt   = (bf16_t*)ws;                    // tiled B: 512*512*2 = 524288 B
    float*  gate = (float*)(ws + 524288);          // 100000*4 B

    k_w1t_tiled<<<dim3(128), dim3(256), 0, stream>>>(W1, bt);
    k_gemm_gate<<<dim3(NBLK), dim3(512), 0, stream>>>(h, bt, b1, W2, b2, gate);
    k_pool<<<dim3(NGRAPH), dim3(256), 0, stream>>>(h, bv, gate, out);
}